// Round 14
// baseline (602.715 us; speedup 1.0000x reference)
//
#include <hip/hip_runtime.h>

#define E_TOT   800000
#define NN      50000
#define FF      64

typedef __attribute__((ext_vector_type(8))) short  short8;
typedef __attribute__((ext_vector_type(4))) float  f32x4;
typedef __attribute__((ext_vector_type(4))) unsigned int u32x4;

__device__ __forceinline__ unsigned short f2bf(float f) {
  union { float f; unsigned int u; } v; v.f = f;
  unsigned int r = v.u + 0x7fffu + ((v.u >> 16) & 1u);
  return (unsigned short)(r >> 16);
}

// pack two f32 -> one u32 of 2 bf16 (RNE), single instruction
__device__ __forceinline__ unsigned int pkbf(float a, float b) {
  unsigned int r;
  asm("v_cvt_pk_bf16_f32 %0, %1, %2" : "=v"(r) : "v"(a), "v"(b));
  return r;
}

__device__ __forceinline__ float bflo(unsigned int u) { return __uint_as_float(u << 16); }
__device__ __forceinline__ float bfhi(unsigned int u) { return __uint_as_float(u & 0xffff0000u); }

__device__ __forceinline__ float sigmoidf_(float x) {
  return 1.f / (1.f + __expf(-x));
}

// nontemporal 16B helpers via ext-vector types (builtin requires ext vectors)
__device__ __forceinline__ f32x4 nt_load_f4(const float* p) {
  return __builtin_nontemporal_load((const f32x4*)p);
}
__device__ __forceinline__ void nt_store_f4(float* p, f32x4 v) {
  __builtin_nontemporal_store(v, (f32x4*)p);
}
__device__ __forceinline__ u32x4 nt_load_u4(const unsigned int* p) {
  return __builtin_nontemporal_load((const u32x4*)p);
}
__device__ __forceinline__ void nt_store_u4(unsigned int* p, u32x4 v) {
  __builtin_nontemporal_store(v, (u32x4*)p);
}

// node_feats f32 -> bf16 table (pairs packed, RNE — identical values to cvt path)
__global__ void cvt_node(const float2* __restrict__ nf, unsigned int* __restrict__ nb) {
  int i = blockIdx.x * 256 + threadIdx.x;           // NN*32 = 1.6M exact
  float2 v = nf[i];
  nb[i] = pkbf(v.x, v.y);
}

// Pack W_mlpt|W_gate [192x64] f32 into MFMA B-fragment order bf16.
__global__ void pack_w(const float* __restrict__ Wm, const float* __restrict__ Wg,
                       unsigned short* __restrict__ Wp) {
  int t = blockIdx.x * 256 + threadIdx.x;
  if (t >= 3072) return;
  int lane = t & 63;
  int kk   = (t >> 6) % 6;
  int mnt  = t / 384;            // 0..7
  const float* W = (mnt >> 2) ? Wg : Wm;
  int nt  = mnt & 3;
  int col = nt * 16 + (lane & 15);
  int kb  = kk * 32 + (lane >> 4) * 8;
  #pragma unroll
  for (int j = 0; j < 8; ++j)
    Wp[t * 8 + j] = f2bf(W[(kb + j) * 64 + col]);
}

__global__ void hist_k(const int* __restrict__ dst, int* __restrict__ counts) {
  int e = blockIdx.x * 256 + threadIdx.x;
  if (e < E_TOT) atomicAdd(&counts[dst[e]], 1);
}

// exclusive scan of counts[NN] -> offs, cursor (single block, 1024 threads; r4-verified)
__global__ __launch_bounds__(1024)
void scan_k(const int* __restrict__ counts, int* __restrict__ offs, int* __restrict__ cursor) {
  __shared__ int wsum[16];
  const int t = threadIdx.x;
  const int CH = 49;                        // 1024*49 >= 50000
  int lo = t * CH, hi = min(lo + CH, NN);
  if (lo > NN) lo = NN;
  int s = 0;
  for (int i = lo; i < hi; ++i) s += counts[i];
  int lane = t & 63, w = t >> 6;
  int v = s;
  #pragma unroll
  for (int dlt = 1; dlt < 64; dlt <<= 1) {
    int u = __shfl_up(v, dlt);
    if (lane >= dlt) v += u;
  }
  if (lane == 63) wsum[w] = v;
  __syncthreads();
  if (t == 0) {
    int a = 0;
    for (int i = 0; i < 16; ++i) { int c = wsum[i]; wsum[i] = a; a += c; }
  }
  __syncthreads();
  int run = v - s + wsum[w];                // exclusive prefix of this chunk
  for (int i = lo; i < hi; ++i) {
    int c = counts[i];
    offs[i] = run; cursor[i] = run;
    run += c;
  }
}

__global__ void fill_k(const int* __restrict__ dst, int* __restrict__ cursor,
                       int* __restrict__ eid) {
  int e = blockIdx.x * 256 + threadIdx.x;
  if (e < E_TOT) {
    int p = atomicAdd(&cursor[dst[e]], 1);
    eid[p] = e;
  }
}

// Gather + stage + GEMM (r12 structure) + shfl-transpose -> Y row-major [E][64]uint
// (uint j = col pair (2j,2j+1); j 0..31 = mlpt, 32..63 = gate).
template <int NB>
__global__ __launch_bounds__(256, 5)
void edge_gemm(const float* __restrict__ nodef, const unsigned short* __restrict__ nodeb,
               const float* __restrict__ edgef,
               const int* __restrict__ src, const int* __restrict__ dst,
               const unsigned short* __restrict__ Wp,
               float* __restrict__ stats,          // 64 slots x 256
               unsigned int* __restrict__ Y,       // row-major [E][64] uint
               float* __restrict__ outE, int write_copy)
{
  __shared__ unsigned short sh[64 * 200];          // row stride 200 ushort = 400 B
  __shared__ float red[4 * 256];                   // separate: no aliasing

  const int tid = threadIdx.x;
  const int e0  = blockIdx.x * 64;
  const int row = tid >> 2;                        // wave-private: row/16 == tid/64
  const int cq  = tid & 3;

  const int s = src[e0 + row], d = dst[e0 + row];
  unsigned short* rowp = &sh[row * 200];

  if constexpr (NB) {
    const unsigned int* qs = (const unsigned int*)(nodeb + (size_t)s * 64) + cq * 8;
    const unsigned int* qd = (const unsigned int*)(nodeb + (size_t)d * 64) + cq * 8;
    u32x4 s0 = *(const u32x4*)qs,       s1 = *(const u32x4*)(qs + 4);
    u32x4 d0 = *(const u32x4*)qd,       d1 = *(const u32x4*)(qd + 4);
    *(u32x4*)(rowp + cq * 16)          = s0;
    *(u32x4*)(rowp + cq * 16 + 8)      = s1;
    *(u32x4*)(rowp + 64 + cq * 16)     = d0;
    *(u32x4*)(rowp + 64 + cq * 16 + 8) = d1;
  } else {
    const float* ps = nodef + (size_t)s * 64 + cq * 4;
    const float* pd = nodef + (size_t)d * 64 + cq * 4;
    #pragma unroll
    for (int it = 0; it < 4; ++it) {
      float4 v0 = *(const float4*)(ps + it * 16);
      float4 v1 = *(const float4*)(pd + it * 16);
      *(uint2*)(rowp + cq * 4 + it * 16)      = make_uint2(pkbf(v0.x, v0.y), pkbf(v0.z, v0.w));
      *(uint2*)(rowp + 64 + cq * 4 + it * 16) = make_uint2(pkbf(v1.x, v1.y), pkbf(v1.z, v1.w));
    }
  }

  // edge part: stream-once loads (nontemporal), feeds staging + fused copy
  const float* pe = edgef + (size_t)(e0 + row) * 64 + cq * 4;
  f32x4 ev[4];
  #pragma unroll
  for (int it = 0; it < 4; ++it) {
    ev[it] = nt_load_f4(pe + it * 16);
    *(uint2*)(rowp + 128 + cq * 4 + it * 16) =
        make_uint2(pkbf(ev[it].x, ev[it].y), pkbf(ev[it].z, ev[it].w));
  }
  if (write_copy) {
    float* op = outE + (size_t)(e0 + row) * 64 + cq * 4;
    #pragma unroll
    for (int it = 0; it < 4; ++it)
      nt_store_f4(op + it * 16, ev[it]);
  }

  // no __syncthreads: wave w reads only LDS rows it wrote. Drain own LDS writes.
  asm volatile("s_waitcnt lgkmcnt(0)" ::: "memory");

  const int w = tid >> 6, lane = tid & 63;
  f32x4 acc[8] = {};
  const unsigned short* abase = &sh[(w * 16 + (lane & 15)) * 200 + (lane >> 4) * 8];
  const short8* wp = (const short8*)Wp;

  #pragma unroll
  for (int kk = 0; kk < 6; ++kk) {
    short8 a = *(const short8*)(abase + kk * 32);
    #pragma unroll
    for (int nt = 0; nt < 8; ++nt) {
      short8 b = wp[(nt * 6 + kk) * 64 + lane];
      acc[nt] = __builtin_amdgcn_mfma_f32_16x16x32_bf16(a, b, acc[nt], 0, 0, 0);
    }
  }

  // own ds_reads complete before overwriting own staging rows
  asm volatile("s_waitcnt lgkmcnt(0)" ::: "memory");

  // shfl-transpose into row-major [64][100]-uint view of sh (wave-private rows)
  unsigned int* shu = (unsigned int*)sh;
  const int colb = lane & 15, rq = lane >> 4, par = colb & 1;
  #pragma unroll
  for (int nt = 0; nt < 8; ++nt) {
    float hv0 = acc[nt][0], hv1 = acc[nt][1], hv2 = acc[nt][2], hv3 = acc[nt][3];
    float pv0 = __shfl_xor(hv0, 1), pv1 = __shfl_xor(hv1, 1);
    float pv2 = __shfl_xor(hv2, 1), pv3 = __shfl_xor(hv3, 1);
    // even lanes own rows rq*4+{0,1}; odd lanes rows rq*4+{2,3}; uint = (even,odd) col pair
    float loA = par ? pv2 : hv0,  hiA = par ? hv2 : pv0;
    float loB = par ? pv3 : hv1,  hiB = par ? hv3 : pv1;
    int r0 = rq * 4 + par * 2;
    int ci = nt * 8 + (colb >> 1);
    shu[(w * 16 + r0)     * 100 + ci] = pkbf(loA, hiA);
    shu[(w * 16 + r0 + 1) * 100 + ci] = pkbf(loB, hiB);
  }

  // column sums / sumsq reduction (red is a separate LDS array; wave-private slots)
  #pragma unroll
  for (int nt = 0; nt < 8; ++nt) {
    float sv = acc[nt][0] + acc[nt][1] + acc[nt][2] + acc[nt][3];
    float qv = acc[nt][0] * acc[nt][0] + acc[nt][1] * acc[nt][1] +
               acc[nt][2] * acc[nt][2] + acc[nt][3] * acc[nt][3];
    sv += __shfl_xor(sv, 16); sv += __shfl_xor(sv, 32);
    qv += __shfl_xor(qv, 16); qv += __shfl_xor(qv, 32);
    if ((lane >> 4) == 0) {
      red[w * 256 + nt * 16 + lane]       = sv;
      red[w * 256 + 128 + nt * 16 + lane] = qv;
    }
  }
  __syncthreads();

  // Y store: 64 rows x 256 B, fully coalesced, nontemporal
  #pragma unroll
  for (int k2 = 0; k2 < 4; ++k2) {
    int k  = tid + k2 * 256;           // 0..1023
    int rw = k >> 4, part = k & 15;
    u32x4 v = *(const u32x4*)&shu[rw * 100 + part * 4];
    nt_store_u4(Y + (size_t)(e0 + rw) * 64 + part * 4, v);
  }

  float v = red[tid] + red[256 + tid] + red[512 + tid] + red[768 + tid];
  atomicAdd(&stats[(blockIdx.x & 63) * 256 + tid], v);
}

__global__ void finalize_edge(const float* __restrict__ stats,
                              const float* __restrict__ g_m, const float* __restrict__ be_m,
                              const float* __restrict__ g_g, const float* __restrict__ be_g,
                              float* __restrict__ coef) {
  int c = threadIdx.x;  // 0..127
  float s = 0.f, q = 0.f;
  for (int sl = 0; sl < 64; ++sl) { s += stats[sl * 256 + c]; q += stats[sl * 256 + 128 + c]; }
  float mu  = s * (1.f / E_TOT);
  float var = fmaxf(q * (1.f / E_TOT) - mu * mu, 0.f);
  float g   = (c < 64) ? g_m[c]  : g_g[c - 64];
  float be  = (c < 64) ? be_m[c] : be_g[c - 64];
  float a   = g * rsqrtf(var + 1e-5f);
  coef[c]       = a;
  coef[128 + c] = be - mu * a;
}

// Pull aggregation: one WAVE per node. Loads the node's Y rows in coalesced
// 256B chunks (4 rows in flight), BN+act in-register (m/g via shfl_xor(8)),
// f32 accumulate, shfl-reduce across row-groups, plain stores. NO scatter atomics.
__global__ __launch_bounds__(256)
void node_sum2(const unsigned int* __restrict__ Yu, const int* __restrict__ eid,
               const int* __restrict__ offs, const int* __restrict__ counts,
               const float* __restrict__ coef, unsigned int* __restrict__ aggu)
{
  const int tid = threadIdx.x;
  const int w = tid >> 6, lane = tid & 63;
  const int n = blockIdx.x * 4 + w;             // grid 12500, NN exact
  const int x = lane & 15, grp = lane >> 4;
  const bool isg = x >= 8;
  const int cb = (x & 7) * 8;                   // col window base (within half)

  float A[8], C[8];
  #pragma unroll
  for (int k = 0; k < 8; ++k) {
    A[k] = coef[(isg ? 64 : 0) + cb + k];
    C[k] = coef[128 + (isg ? 64 : 0) + cb + k];
  }

  const int st = offs[n], deg = counts[n];
  float a[8] = {};

  for (int base = 0; base < deg; base += 16) {
    #pragma unroll
    for (int i = 0; i < 4; ++i) {
      int p = base + i * 4 + grp;               // uniform across the 16-lane group
      bool ok = p < deg;
      int e = eid[st + (ok ? p : 0)];
      u32x4 y = nt_load_u4(Yu + (size_t)e * 64 + x * 4);
      float r[8];
      #pragma unroll
      for (int j = 0; j < 4; ++j) {
        unsigned int u = y[j];
        float v0 = fmaf(bflo(u), A[2 * j],     C[2 * j]);
        float v1 = fmaf(bfhi(u), A[2 * j + 1], C[2 * j + 1]);
        if (isg) {
          r[2 * j]     = (v0 > 20.f) ? v0 : __logf(1.f + __expf(v0));
          r[2 * j + 1] = (v1 > 20.f) ? v1 : __logf(1.f + __expf(v1));
        } else {
          r[2 * j]     = 1.f / (1.f + __expf(-v0));
          r[2 * j + 1] = 1.f / (1.f + __expf(-v1));
        }
      }
      #pragma unroll
      for (int k = 0; k < 8; ++k) {
        float pr = __shfl_xor(r[k], 8);         // partner half (m<->g), same cols
        float h = r[k] * pr;
        a[k] += ok ? h : 0.f;
      }
    }
  }

  #pragma unroll
  for (int k = 0; k < 8; ++k) {
    a[k] += __shfl_xor(a[k], 16);
    a[k] += __shfl_xor(a[k], 32);
  }
  if (lane < 8) {                               // lanes 0..7 cover cols 0..63
    u32x4 o;
    o.x = pkbf(a[0], a[1]); o.y = pkbf(a[2], a[3]);
    o.z = pkbf(a[4], a[5]); o.w = pkbf(a[6], a[7]);
    *(u32x4*)(aggu + (size_t)n * 32 + lane * 4) = o;
  }
}

// stats over bf16 agg: thread handles a column PAIR (cp = tid&31 -> cols 2cp, 2cp+1)
__global__ void node_stats(const unsigned int* __restrict__ aggu, float* __restrict__ nstats) {
  __shared__ float rs0[256], rq0[256], rs1[256], rq1[256];
  int tid = threadIdx.x;
  int cp = tid & 31;
  float s0 = 0.f, q0 = 0.f, s1 = 0.f, q1 = 0.f;
  for (int r = blockIdx.x * 8 + (tid >> 5); r < NN; r += gridDim.x * 8) {
    unsigned int u = aggu[r * 32 + cp];
    float v0 = bflo(u), v1 = bfhi(u);
    s0 += v0; q0 += v0 * v0; s1 += v1; q1 += v1 * v1;
  }
  rs0[tid] = s0; rq0[tid] = q0; rs1[tid] = s1; rq1[tid] = q1;
  __syncthreads();
  if (tid < 32) {
    s0 = 0.f; q0 = 0.f; s1 = 0.f; q1 = 0.f;
    #pragma unroll
    for (int k = 0; k < 8; ++k) {
      s0 += rs0[tid + 32 * k]; q0 += rq0[tid + 32 * k];
      s1 += rs1[tid + 32 * k]; q1 += rq1[tid + 32 * k];
    }
    int slot = blockIdx.x & 31;
    atomicAdd(&nstats[slot * 128 + 2 * tid],      s0);
    atomicAdd(&nstats[slot * 128 + 2 * tid + 1],  s1);
    atomicAdd(&nstats[slot * 128 + 64 + 2 * tid],     q0);
    atomicAdd(&nstats[slot * 128 + 64 + 2 * tid + 1], q1);
  }
}

__global__ void finalize_node(const float* __restrict__ nstats,
                              const float* __restrict__ g_n, const float* __restrict__ be_n,
                              float* __restrict__ coefn) {
  int c = threadIdx.x;  // 0..63
  float s = 0.f, q = 0.f;
  for (int sl = 0; sl < 32; ++sl) { s += nstats[sl * 128 + c]; q += nstats[sl * 128 + 64 + c]; }
  float mu  = s * (1.f / NN);
  float var = fmaxf(q * (1.f / NN) - mu * mu, 0.f);
  float a   = g_n[c] * rsqrtf(var + 1e-5f);
  coefn[c]      = a;
  coefn[64 + c] = be_n[c] - mu * a;
}

__global__ void node_out_k(float* __restrict__ out, const unsigned int* __restrict__ aggu,
                           const float* __restrict__ nodef, const float* __restrict__ coefn) {
  int i  = blockIdx.x * 256 + threadIdx.x;   // one float4 of output per thread
  int cb = (i & 15) * 4;
  uint2  u  = ((const uint2*)aggu)[i];
  float4 nf = ((const float4*)nodef)[i];
  float4 r;
  r.x = sigmoidf_(coefn[cb + 0] * bflo(u.x) + coefn[64 + cb + 0] + nf.x);
  r.y = sigmoidf_(coefn[cb + 1] * bfhi(u.x) + coefn[64 + cb + 1] + nf.y);
  r.z = sigmoidf_(coefn[cb + 2] * bflo(u.y) + coefn[64 + cb + 2] + nf.z);
  r.w = sigmoidf_(coefn[cb + 3] * bfhi(u.y) + coefn[64 + cb + 3] + nf.w);
  ((float4*)out)[i] = r;
}

extern "C" void kernel_launch(void* const* d_in, const int* in_sizes, int n_in,
                              void* d_out, int out_size, void* d_ws, size_t ws_size,
                              hipStream_t stream) {
  const float* nodef = (const float*)d_in[0];
  const float* edgef = (const float*)d_in[1];
  const int*   src   = (const int*)d_in[2];
  const int*   dst   = (const int*)d_in[3];
  const float* W_m   = (const float*)d_in[4];
  const float* g_m   = (const float*)d_in[6];
  const float* be_m  = (const float*)d_in[7];
  const float* W_g   = (const float*)d_in[8];
  const float* g_g   = (const float*)d_in[10];
  const float* be_g  = (const float*)d_in[11];
  const float* g_n   = (const float*)d_in[12];
  const float* be_n  = (const float*)d_in[13];

  float* out  = (float*)d_out;
  float* outE = out + (size_t)NN * FF;                // edge output region

  // CSR arrays live in the dead node region of d_out (written last by node_out_k)
  char* od = (char*)d_out;
  int* counts = (int*)(od + 0x000000);                 // 200 KB
  int* offs   = (int*)(od + 0x040000);                 // 200 KB
  int* cursor = (int*)(od + 0x080000);                 // 200 KB
  int* eid    = (int*)(od + 0x0C0000);                 // 3.2 MB

  char* ws = (char*)d_ws;
  unsigned short* aggb = (unsigned short*)ws;          // [NN*64] bf16 = 6.4 MB
  float* stats  = (float*)(ws + 0x640000);             // 64 KB
  float* coef   = (float*)(ws + 0x650000);             // 1 KB
  float* nstats = (float*)(ws + 0x651000);             // 16 KB
  float* coefn  = (float*)(ws + 0x655000);             // 512 B
  unsigned short* Wp = (unsigned short*)(ws + 0x656000); // 48 KB

  const size_t y_bytes = (size_t)E_TOT * 64 * 4;      // 204.8 MB
  const int y_in_ws = (ws_size >= (size_t)0x700000 + y_bytes);
  unsigned int* Y = y_in_ws ? (unsigned int*)(ws + 0x700000) : (unsigned int*)outE;

  // bf16 node table past Y (fallback to f32 staging path if too small)
  const size_t nb_off = y_in_ws ? ((size_t)0x700000 + y_bytes) : (size_t)0x700000;
  const int use_nb = (ws_size >= nb_off + (size_t)NN * FF * 2);
  unsigned short* nodeb = (unsigned short*)(ws + nb_off);

  hipMemsetAsync(aggb, 0, (size_t)NN * FF * 2, stream);
  hipMemsetAsync(stats, 0, 0x15200, stream);          // stats+coef+nstats+coefn
  hipMemsetAsync(counts, 0, NN * sizeof(int), stream);

  pack_w<<<12, 256, 0, stream>>>(W_m, W_g, Wp);
  hist_k<<<(E_TOT + 255) / 256, 256, 0, stream>>>(dst, counts);
  if (use_nb) {
    cvt_node<<<NN * 32 / 256, 256, 0, stream>>>((const float2*)nodef, (unsigned int*)nodeb);
    edge_gemm<1><<<E_TOT / 64, 256, 0, stream>>>(nodef, nodeb, edgef, src, dst, Wp,
                                                 stats, Y, outE, y_in_ws);
  } else {
    edge_gemm<0><<<E_TOT / 64, 256, 0, stream>>>(nodef, nodeb, edgef, src, dst, Wp,
                                                 stats, Y, outE, y_in_ws);
  }
  scan_k<<<1, 1024, 0, stream>>>(counts, offs, cursor);
  finalize_edge<<<1, 128, 0, stream>>>(stats, g_m, be_m, g_g, be_g, coef);
  fill_k<<<(E_TOT + 255) / 256, 256, 0, stream>>>(dst, cursor, eid);
  node_sum2<<<NN / 4, 256, 0, stream>>>(Y, eid, offs, counts, coef, (unsigned int*)aggb);
  if (!y_in_ws) {
    // Y occupied the edge-output region; overwrite with the verbatim copy now
    hipMemcpyAsync(outE, edgef, (size_t)E_TOT * FF * sizeof(float),
                   hipMemcpyDeviceToDevice, stream);
  }
  node_stats<<<512, 256, 0, stream>>>((const unsigned int*)aggb, nstats);
  finalize_node<<<1, 64, 0, stream>>>(nstats, g_n, be_n, coefn);
  node_out_k<<<NN * FF / 4 / 256, 256, 0, stream>>>(out, (const unsigned int*)aggb,
                                                    nodef, coefn);
}

// Round 15
// 379.971 us; speedup vs baseline: 1.5862x; 1.5862x over previous
//
#include <hip/hip_runtime.h>

#define E_TOT   800000
#define NN      50000
#define FF      64

typedef __attribute__((ext_vector_type(8))) short  short8;
typedef __attribute__((ext_vector_type(4))) float  f32x4;
typedef __attribute__((ext_vector_type(4))) unsigned int u32x4;

__device__ __forceinline__ unsigned short f2bf(float f) {
  union { float f; unsigned int u; } v; v.f = f;
  unsigned int r = v.u + 0x7fffu + ((v.u >> 16) & 1u);
  return (unsigned short)(r >> 16);
}

// pack two f32 -> one u32 of 2 bf16 (RNE), single instruction
__device__ __forceinline__ unsigned int pkbf(float a, float b) {
  unsigned int r;
  asm("v_cvt_pk_bf16_f32 %0, %1, %2" : "=v"(r) : "v"(a), "v"(b));
  return r;
}

// packed bf16 atomic add (fire-and-forget, device scope)
__device__ __forceinline__ void atomic_pk_bf16(unsigned short* p, unsigned int v) {
  asm volatile("global_atomic_pk_add_bf16 %0, %1, off" :: "v"(p), "v"(v) : "memory");
}

__device__ __forceinline__ float bflo(unsigned int u) { return __uint_as_float(u << 16); }
__device__ __forceinline__ float bfhi(unsigned int u) { return __uint_as_float(u & 0xffff0000u); }

__device__ __forceinline__ float sigmoidf_(float x) {
  return 1.f / (1.f + __expf(-x));
}

// nontemporal 16B helpers via ext-vector types (builtin requires ext vectors)
__device__ __forceinline__ f32x4 nt_load_f4(const float* p) {
  return __builtin_nontemporal_load((const f32x4*)p);
}
__device__ __forceinline__ void nt_store_f4(float* p, f32x4 v) {
  __builtin_nontemporal_store(v, (f32x4*)p);
}
__device__ __forceinline__ u32x4 nt_load_u4(const unsigned int* p) {
  return __builtin_nontemporal_load((const u32x4*)p);
}
__device__ __forceinline__ void nt_store_u4(unsigned int* p, u32x4 v) {
  __builtin_nontemporal_store(v, (u32x4*)p);
}

// node_feats f32 -> bf16 table (pairs packed, RNE — identical values to staged path)
__global__ void cvt_node(const float2* __restrict__ nf, unsigned int* __restrict__ nb) {
  int i = blockIdx.x * 256 + threadIdx.x;           // NN*32 = 1.6M exact
  float2 v = nf[i];
  nb[i] = pkbf(v.x, v.y);
}

// Pack W_mlpt|W_gate [192x64] f32 into MFMA B-fragment order bf16.
__global__ void pack_w(const float* __restrict__ Wm, const float* __restrict__ Wg,
                       unsigned short* __restrict__ Wp) {
  int t = blockIdx.x * 256 + threadIdx.x;
  if (t >= 3072) return;
  int lane = t & 63;
  int kk   = (t >> 6) % 6;
  int mnt  = t / 384;            // 0..7
  const float* W = (mnt >> 2) ? Wg : Wm;
  int nt  = mnt & 3;
  int col = nt * 16 + (lane & 15);
  int kb  = kk * 32 + (lane >> 4) * 8;
  #pragma unroll
  for (int j = 0; j < 8; ++j)
    Wp[t * 8 + j] = f2bf(W[(kb + j) * 64 + col]);
}

// Gather + stage + GEMM (r7 structure: wave-private staging rows, no pre-MFMA
// barrier). NB=1: node parts staged from bf16 table (half the gather bytes).
template <int NB>
__global__ __launch_bounds__(256, 5)
void edge_gemm(const float* __restrict__ nodef, const unsigned short* __restrict__ nodeb,
               const float* __restrict__ edgef,
               const int* __restrict__ src, const int* __restrict__ dst,
               const unsigned short* __restrict__ Wp,
               float* __restrict__ stats,          // 64 slots x 256
               unsigned int* __restrict__ Yw,      // reg-layout Y (uint units)
               float* __restrict__ outE, int write_copy)
{
  __shared__ unsigned short sh[64 * 200];          // row stride 200 ushort = 400 B
  __shared__ float red[4 * 256];

  const int tid = threadIdx.x;
  const int e0  = blockIdx.x * 64;
  const int row = tid >> 2;                        // wave-private: row/16 == tid/64
  const int cq  = tid & 3;

  const int s = src[e0 + row], d = dst[e0 + row];
  unsigned short* rowp = &sh[row * 200];

  if constexpr (NB) {
    const unsigned int* qs = (const unsigned int*)(nodeb + (size_t)s * 64) + cq * 8;
    const unsigned int* qd = (const unsigned int*)(nodeb + (size_t)d * 64) + cq * 8;
    u32x4 s0 = *(const u32x4*)qs,       s1 = *(const u32x4*)(qs + 4);
    u32x4 d0 = *(const u32x4*)qd,       d1 = *(const u32x4*)(qd + 4);
    *(u32x4*)(rowp + cq * 16)          = s0;
    *(u32x4*)(rowp + cq * 16 + 8)      = s1;
    *(u32x4*)(rowp + 64 + cq * 16)     = d0;
    *(u32x4*)(rowp + 64 + cq * 16 + 8) = d1;
  } else {
    const float* ps = nodef + (size_t)s * 64 + cq * 4;
    const float* pd = nodef + (size_t)d * 64 + cq * 4;
    #pragma unroll
    for (int it = 0; it < 4; ++it) {
      float4 v0 = *(const float4*)(ps + it * 16);
      float4 v1 = *(const float4*)(pd + it * 16);
      *(uint2*)(rowp + cq * 4 + it * 16)      = make_uint2(pkbf(v0.x, v0.y), pkbf(v0.z, v0.w));
      *(uint2*)(rowp + 64 + cq * 4 + it * 16) = make_uint2(pkbf(v1.x, v1.y), pkbf(v1.z, v1.w));
    }
  }

  // edge part: stream-once loads (nontemporal), feeds staging + fused copy
  const float* pe = edgef + (size_t)(e0 + row) * 64 + cq * 4;
  f32x4 ev[4];
  #pragma unroll
  for (int it = 0; it < 4; ++it) {
    ev[it] = nt_load_f4(pe + it * 16);
    *(uint2*)(rowp + 128 + cq * 4 + it * 16) =
        make_uint2(pkbf(ev[it].x, ev[it].y), pkbf(ev[it].z, ev[it].w));
  }
  if (write_copy) {
    float* op = outE + (size_t)(e0 + row) * 64 + cq * 4;
    #pragma unroll
    for (int it = 0; it < 4; ++it)
      nt_store_f4(op + it * 16, ev[it]);
  }

  // no __syncthreads: wave w reads only LDS rows it wrote. Drain own LDS writes.
  asm volatile("s_waitcnt lgkmcnt(0)" ::: "memory");

  const int w = tid >> 6, lane = tid & 63;
  f32x4 acc[8] = {};
  const unsigned short* abase = &sh[(w * 16 + (lane & 15)) * 200 + (lane >> 4) * 8];
  const short8* wp = (const short8*)Wp;

  #pragma unroll
  for (int kk = 0; kk < 6; ++kk) {
    short8 a = *(const short8*)(abase + kk * 32);
    #pragma unroll
    for (int nt = 0; nt < 8; ++nt) {
      short8 b = wp[(nt * 6 + kk) * 64 + lane];
      acc[nt] = __builtin_amdgcn_mfma_f32_16x16x32_bf16(a, b, acc[nt], 0, 0, 0);
    }
  }

  // write Y as bf16 in MFMA-register layout (coalesced, nontemporal)
  unsigned int* yb = Yw + ((((size_t)blockIdx.x * 4 + w) * 4) * 64 + lane) * 4;
  #pragma unroll
  for (int ntp = 0; ntp < 4; ++ntp) {
    u32x4 q;
    q.x = pkbf(acc[2 * ntp][0],     acc[2 * ntp][1]);
    q.y = pkbf(acc[2 * ntp][2],     acc[2 * ntp][3]);
    q.z = pkbf(acc[2 * ntp + 1][0], acc[2 * ntp + 1][1]);
    q.w = pkbf(acc[2 * ntp + 1][2], acc[2 * ntp + 1][3]);
    nt_store_u4(yb + ntp * 64 * 4, q);
  }

  // column sums / sumsq reduction (red writes wave-private; barrier before cross-read)
  #pragma unroll
  for (int nt = 0; nt < 8; ++nt) {
    float sv = acc[nt][0] + acc[nt][1] + acc[nt][2] + acc[nt][3];
    float qv = acc[nt][0] * acc[nt][0] + acc[nt][1] * acc[nt][1] +
               acc[nt][2] * acc[nt][2] + acc[nt][3] * acc[nt][3];
    sv += __shfl_xor(sv, 16); sv += __shfl_xor(sv, 32);
    qv += __shfl_xor(qv, 16); qv += __shfl_xor(qv, 32);
    if ((lane >> 4) == 0) {
      red[w * 256 + nt * 16 + lane]       = sv;
      red[w * 256 + 128 + nt * 16 + lane] = qv;
    }
  }
  __syncthreads();
  float v = red[tid] + red[256 + tid] + red[512 + tid] + red[768 + tid];
  atomicAdd(&stats[(blockIdx.x & 63) * 256 + tid], v);
}

__global__ void finalize_edge(const float* __restrict__ stats,
                              const float* __restrict__ g_m, const float* __restrict__ be_m,
                              const float* __restrict__ g_g, const float* __restrict__ be_g,
                              float* __restrict__ coef) {
  int c = threadIdx.x;  // 0..127
  float s = 0.f, q = 0.f;
  for (int sl = 0; sl < 64; ++sl) { s += stats[sl * 256 + c]; q += stats[sl * 256 + 128 + c]; }
  float mu  = s * (1.f / E_TOT);
  float var = fmaxf(q * (1.f / E_TOT) - mu * mu, 0.f);
  float g   = (c < 64) ? g_m[c]  : g_g[c - 64];
  float be  = (c < 64) ? be_m[c] : be_g[c - 64];
  float a   = g * rsqrtf(var + 1e-5f);
  coef[c]       = a;
  coef[128 + c] = be - mu * a;
}

// Read Y (reg layout, nontemporal), folded BN + activations, pk-bf16 scatter.
__global__ __launch_bounds__(256)
void edge_apply(const unsigned int* __restrict__ Yw, const int* __restrict__ dst,
                const float* __restrict__ coef,  // a[128], c[128]
                unsigned short* __restrict__ aggb)
{
  const int tid = threadIdx.x;
  const int w = tid >> 6, lane = tid & 63;
  const int e0 = blockIdx.x * 64;
  const int r0 = w * 16 + ((lane >> 4) << 2);
  const int4 dn = *(const int4*)&dst[e0 + r0];
  const int colb = lane & 15;
  const int par  = colb & 1;

  const unsigned int* yb = Yw + ((((size_t)blockIdx.x * 4 + w) * 4) * 64 + lane) * 4;
  u32x4 qm0 = nt_load_u4(yb);
  u32x4 qm1 = nt_load_u4(yb + 64 * 4);
  u32x4 qg0 = nt_load_u4(yb + 128 * 4);
  u32x4 qg1 = nt_load_u4(yb + 192 * 4);
  const unsigned int um[8] = {qm0.x, qm0.y, qm0.z, qm0.w, qm1.x, qm1.y, qm1.z, qm1.w};
  const unsigned int ug[8] = {qg0.x, qg0.y, qg0.z, qg0.w, qg1.x, qg1.y, qg1.z, qg1.w};
  const int dr[4] = {dn.x, dn.y, dn.z, dn.w};

  #pragma unroll
  for (int ntm = 0; ntm < 4; ++ntm) {
    const int col = ntm * 16 + colb;
    const float am = coef[col],      cm = coef[128 + col];
    const float ag = coef[64 + col], cg = coef[192 + col];
    float hv[4];
    #pragma unroll
    for (int p = 0; p < 2; ++p) {
      unsigned int m = um[ntm * 2 + p], g = ug[ntm * 2 + p];
      #pragma unroll
      for (int h = 0; h < 2; ++h) {
        float mv = h ? bfhi(m) : bflo(m);
        float gv = h ? bfhi(g) : bflo(g);
        float ym = fmaf(mv, am, cm);
        float yg = fmaf(gv, ag, cg);
        float sig = sigmoidf_(ym);
        float sp  = (yg > 20.f) ? yg : __logf(1.f + __expf(yg));
        hv[2 * p + h] = sig * sp;
      }
    }
    // exchange with lane-partner (col ^ 1); even lanes scatter rows 0,1; odd rows 2,3
    float pv[4];
    #pragma unroll
    for (int rr = 0; rr < 4; ++rr) pv[rr] = __shfl_xor(hv[rr], 1);
    const int colp = ntm * 16 + (colb & ~1);
    #pragma unroll
    for (int rr = 0; rr < 2; ++rr) {
      int rx = par * 2 + rr;
      float lo = par ? pv[rx] : hv[rx];
      float hi = par ? hv[rx] : pv[rx];
      atomic_pk_bf16(&aggb[(size_t)dr[rx] * 64 + colp], pkbf(lo, hi));
    }
  }
}

// stats over bf16 agg: thread handles a column PAIR (cp = tid&31 -> cols 2cp, 2cp+1)
__global__ void node_stats(const unsigned int* __restrict__ aggu, float* __restrict__ nstats) {
  __shared__ float rs0[256], rq0[256], rs1[256], rq1[256];
  int tid = threadIdx.x;
  int cp = tid & 31;
  float s0 = 0.f, q0 = 0.f, s1 = 0.f, q1 = 0.f;
  for (int r = blockIdx.x * 8 + (tid >> 5); r < NN; r += gridDim.x * 8) {
    unsigned int u = aggu[r * 32 + cp];
    float v0 = bflo(u), v1 = bfhi(u);
    s0 += v0; q0 += v0 * v0; s1 += v1; q1 += v1 * v1;
  }
  rs0[tid] = s0; rq0[tid] = q0; rs1[tid] = s1; rq1[tid] = q1;
  __syncthreads();
  if (tid < 32) {
    s0 = 0.f; q0 = 0.f; s1 = 0.f; q1 = 0.f;
    #pragma unroll
    for (int k = 0; k < 8; ++k) {
      s0 += rs0[tid + 32 * k]; q0 += rq0[tid + 32 * k];
      s1 += rs1[tid + 32 * k]; q1 += rq1[tid + 32 * k];
    }
    int slot = blockIdx.x & 31;
    atomicAdd(&nstats[slot * 128 + 2 * tid],      s0);
    atomicAdd(&nstats[slot * 128 + 2 * tid + 1],  s1);
    atomicAdd(&nstats[slot * 128 + 64 + 2 * tid],     q0);
    atomicAdd(&nstats[slot * 128 + 64 + 2 * tid + 1], q1);
  }
}

__global__ void finalize_node(const float* __restrict__ nstats,
                              const float* __restrict__ g_n, const float* __restrict__ be_n,
                              float* __restrict__ coefn) {
  int c = threadIdx.x;  // 0..63
  float s = 0.f, q = 0.f;
  for (int sl = 0; sl < 32; ++sl) { s += nstats[sl * 128 + c]; q += nstats[sl * 128 + 64 + c]; }
  float mu  = s * (1.f / NN);
  float var = fmaxf(q * (1.f / NN) - mu * mu, 0.f);
  float a   = g_n[c] * rsqrtf(var + 1e-5f);
  coefn[c]      = a;
  coefn[64 + c] = be_n[c] - mu * a;
}

__global__ void node_out_k(float* __restrict__ out, const unsigned int* __restrict__ aggu,
                           const float* __restrict__ nodef, const float* __restrict__ coefn) {
  int i  = blockIdx.x * 256 + threadIdx.x;   // one float4 of output per thread
  int cb = (i & 15) * 4;
  uint2  u  = ((const uint2*)aggu)[i];
  float4 nf = ((const float4*)nodef)[i];
  float4 r;
  r.x = sigmoidf_(coefn[cb + 0] * bflo(u.x) + coefn[64 + cb + 0] + nf.x);
  r.y = sigmoidf_(coefn[cb + 1] * bfhi(u.x) + coefn[64 + cb + 1] + nf.y);
  r.z = sigmoidf_(coefn[cb + 2] * bflo(u.y) + coefn[64 + cb + 2] + nf.z);
  r.w = sigmoidf_(coefn[cb + 3] * bfhi(u.y) + coefn[64 + cb + 3] + nf.w);
  ((float4*)out)[i] = r;
}

extern "C" void kernel_launch(void* const* d_in, const int* in_sizes, int n_in,
                              void* d_out, int out_size, void* d_ws, size_t ws_size,
                              hipStream_t stream) {
  const float* nodef = (const float*)d_in[0];
  const float* edgef = (const float*)d_in[1];
  const int*   src   = (const int*)d_in[2];
  const int*   dst   = (const int*)d_in[3];
  const float* W_m   = (const float*)d_in[4];
  const float* g_m   = (const float*)d_in[6];
  const float* be_m  = (const float*)d_in[7];
  const float* W_g   = (const float*)d_in[8];
  const float* g_g   = (const float*)d_in[10];
  const float* be_g  = (const float*)d_in[11];
  const float* g_n   = (const float*)d_in[12];
  const float* be_n  = (const float*)d_in[13];

  float* out  = (float*)d_out;
  float* outE = out + (size_t)NN * FF;                // edge output region

  char* ws = (char*)d_ws;
  unsigned short* aggb = (unsigned short*)ws;          // [NN*64] bf16 = 6.4 MB
  float* stats  = (float*)(ws + 0x640000);             // 64 KB
  float* coef   = (float*)(ws + 0x650000);             // 1 KB
  float* nstats = (float*)(ws + 0x651000);             // 16 KB
  float* coefn  = (float*)(ws + 0x655000);             // 512 B
  unsigned short* Wp = (unsigned short*)(ws + 0x656000); // 48 KB

  const size_t y_bytes = (size_t)E_TOT * 128 * 2;     // 204.8 MB
  const int y_in_ws = (ws_size >= (size_t)0x700000 + y_bytes);
  unsigned int* Yw = y_in_ws ? (unsigned int*)(ws + 0x700000) : (unsigned int*)outE;

  // bf16 node table in the region past Y (fallback to f32 path if too small)
  const size_t nb_off = y_in_ws ? ((size_t)0x700000 + y_bytes) : (size_t)0x700000;
  const int use_nb = (ws_size >= nb_off + (size_t)NN * FF * 2);
  unsigned short* nodeb = (unsigned short*)(ws + nb_off);

  hipMemsetAsync(aggb, 0, (size_t)NN * FF * 2, stream);
  hipMemsetAsync(stats, 0, 0x15200, stream);          // stats+coef+nstats+coefn

  pack_w<<<12, 256, 0, stream>>>(W_m, W_g, Wp);
  if (use_nb) {
    cvt_node<<<NN * 32 / 256, 256, 0, stream>>>((const float2*)nodef, (unsigned int*)nodeb);
    edge_gemm<1><<<E_TOT / 64, 256, 0, stream>>>(nodef, nodeb, edgef, src, dst, Wp,
                                                 stats, Yw, outE, y_in_ws);
  } else {
    edge_gemm<0><<<E_TOT / 64, 256, 0, stream>>>(nodef, nodeb, edgef, src, dst, Wp,
                                                 stats, Yw, outE, y_in_ws);
  }
  finalize_edge<<<1, 128, 0, stream>>>(stats, g_m, be_m, g_g, be_g, coef);
  edge_apply<<<E_TOT / 64, 256, 0, stream>>>(Yw, dst, coef, aggb);
  if (!y_in_ws) {
    hipMemcpyAsync(outE, edgef, (size_t)E_TOT * FF * sizeof(float),
                   hipMemcpyDeviceToDevice, stream);
  }
  node_stats<<<512, 256, 0, stream>>>((const unsigned int*)aggb, nstats);
  finalize_node<<<1, 64, 0, stream>>>(nstats, g_n, be_n, coefn);
  node_out_k<<<NN * FF / 4 / 256, 256, 0, stream>>>(out, (const unsigned int*)aggb,
                                                    nodef, coefn);
}